// Round 1
// baseline (901.636 us; speedup 1.0000x reference)
//
#include <hip/hip_runtime.h>
#include <math.h>

#define DD 768
#define TILE_D 128
#define TOPK 10
#define NBLK_MAX 768

// ---------------------------------------------------------------------------
// top-10 sorted insert, fully unrolled (compile-time indices -> stays in VGPRs)
// ---------------------------------------------------------------------------
__device__ __forceinline__ void topk_insert(float (&sc)[TOPK], int (&id)[TOPK],
                                            float v, int nid) {
    if (v <= sc[TOPK - 1]) return;
#pragma unroll
    for (int j = TOPK - 1; j >= 1; --j) {
        bool gtj   = v > sc[j];
        bool gtjm1 = v > sc[j - 1];
        float cs = gtjm1 ? sc[j - 1] : v;
        int   ci = gtjm1 ? id[j - 1] : nid;
        sc[j] = gtj ? cs : sc[j];
        id[j] = gtj ? ci : id[j];
    }
    bool gt0 = v > sc[0];
    sc[0] = gt0 ? v : sc[0];
    id[0] = gt0 ? nid : id[0];
}

// ---------------------------------------------------------------------------
// Phase 0: L2-normalize the queries into workspace (64 rows x 768)
// ---------------------------------------------------------------------------
__global__ void qnorm_kernel(const float* __restrict__ q, float* __restrict__ qn, int Q) {
    const int row = blockIdx.x;
    const int t = threadIdx.x;  // 256
    float vals[3];
    float s = 0.f;
    if (row < Q) {
#pragma unroll
        for (int i = 0; i < 3; ++i) {
            vals[i] = q[row * DD + i * 256 + t];
            s += vals[i] * vals[i];
        }
    } else {
        vals[0] = vals[1] = vals[2] = 0.f;
    }
#pragma unroll
    for (int o = 32; o; o >>= 1) s += __shfl_down(s, o);
    __shared__ float red[4];
    if ((t & 63) == 0) red[t >> 6] = s;
    __syncthreads();
    float tot = red[0] + red[1] + red[2] + red[3];
    float inv = 1.f / fmaxf(sqrtf(tot), 1e-12f);
#pragma unroll
    for (int i = 0; i < 3; ++i) qn[row * DD + i * 256 + t] = vals[i] * inv;
}

// ---------------------------------------------------------------------------
// Phase 1: scores for 64 queries x 128-doc tiles (fp32 vector GEMM in LDS),
// doc norms accumulated during staging, per-block per-query running top-10.
// LDS: qs[64][68] (pad->2-way max) + ds[64 k][128 doc] (k-major, conflict-free)
//      scores[64][129] overlays the same buffer after compute.
// ---------------------------------------------------------------------------
__global__ __launch_bounds__(256, 3)
void score_kernel(const float* __restrict__ qn, const float* __restrict__ docs,
                  float* __restrict__ cand_sc, int* __restrict__ cand_id,
                  int Ndocs, int ntiles, int Q) {
    __shared__ float smem[12544];   // 50176 B
    __shared__ float dnorm[TILE_D];
    float* qs  = smem;            // [64][68]
    float* dsb = smem + 4352;     // [64][128]  (k-major)
    float* scb = smem;            // [64][129]  overlay

    const int tid = threadIdx.x;
    const int tq = tid >> 4, td = tid & 15;
    const int q0 = tq * 4, d0 = td * 8;

    float sc[TOPK];
    int   id[TOPK];
#pragma unroll
    for (int j = 0; j < TOPK; ++j) { sc[j] = -INFINITY; id[j] = 0; }

    for (int tile = blockIdx.x; tile < ntiles; tile += gridDim.x) {
        const int d0g = tile * TILE_D;
        float acc[4][8];
#pragma unroll
        for (int a = 0; a < 4; ++a)
#pragma unroll
            for (int b = 0; b < 8; ++b) acc[a][b] = 0.f;
        float dnp = 0.f;  // this thread's doc-sumsq partial (doc = tid&127)

        for (int kk = 0; kk < DD; kk += 64) {
            // ---- stage queries: 64 rows x 64 k  (1024 float4) ----
#pragma unroll
            for (int i = 0; i < 4; ++i) {
                int idx = i * 256 + tid;
                int row = idx >> 4, c4 = idx & 15;
                float4 v = *(const float4*)(qn + row * DD + kk + c4 * 4);
                *(float4*)(qs + row * 68 + c4 * 4) = v;
            }
            // ---- stage docs transposed: [k][doc] (2048 float4) ----
#pragma unroll
            for (int i = 0; i < 8; ++i) {
                int idx = i * 256 + tid;
                int r = idx & 127, j = idx >> 7;
                int gd = d0g + r;
                float4 v = make_float4(0.f, 0.f, 0.f, 0.f);
                if (gd < Ndocs)
                    v = *(const float4*)(docs + (size_t)gd * DD + kk + j * 4);
                dnp += v.x * v.x + v.y * v.y + v.z * v.z + v.w * v.w;
                dsb[(j * 4 + 0) * 128 + r] = v.x;
                dsb[(j * 4 + 1) * 128 + r] = v.y;
                dsb[(j * 4 + 2) * 128 + r] = v.z;
                dsb[(j * 4 + 3) * 128 + r] = v.w;
            }
            __syncthreads();
            // ---- compute: 4 queries x 8 docs per thread ----
            for (int k4 = 0; k4 < 16; ++k4) {
                float4 qv[4];
#pragma unroll
                for (int qi = 0; qi < 4; ++qi)
                    qv[qi] = *(const float4*)(qs + (q0 + qi) * 68 + k4 * 4);
#pragma unroll
                for (int c = 0; c < 4; ++c) {
                    const float* dr = dsb + (k4 * 4 + c) * 128 + d0;
                    float4 dv0 = *(const float4*)(dr);
                    float4 dv1 = *(const float4*)(dr + 4);
#pragma unroll
                    for (int qi = 0; qi < 4; ++qi) {
                        float qq = (c == 0) ? qv[qi].x : (c == 1) ? qv[qi].y
                                 : (c == 2) ? qv[qi].z : qv[qi].w;
                        acc[qi][0] = fmaf(qq, dv0.x, acc[qi][0]);
                        acc[qi][1] = fmaf(qq, dv0.y, acc[qi][1]);
                        acc[qi][2] = fmaf(qq, dv0.z, acc[qi][2]);
                        acc[qi][3] = fmaf(qq, dv0.w, acc[qi][3]);
                        acc[qi][4] = fmaf(qq, dv1.x, acc[qi][4]);
                        acc[qi][5] = fmaf(qq, dv1.y, acc[qi][5]);
                        acc[qi][6] = fmaf(qq, dv1.z, acc[qi][6]);
                        acc[qi][7] = fmaf(qq, dv1.w, acc[qi][7]);
                    }
                }
            }
            __syncthreads();
        }
        // ---- combine doc-norm partials: doc r = tid&127, two threads per doc ----
        if (tid < 128) dnorm[tid] = dnp;
        __syncthreads();
        if (tid >= 128) dnorm[tid - 128] += dnp;
        __syncthreads();
        // ---- scale by 1/max(||d||,eps), write scores to LDS ----
        float rs[8];
#pragma unroll
        for (int di = 0; di < 8; ++di)
            rs[di] = 1.f / fmaxf(sqrtf(dnorm[d0 + di]), 1e-12f);
#pragma unroll
        for (int qi = 0; qi < 4; ++qi)
#pragma unroll
            for (int di = 0; di < 8; ++di)
                scb[(q0 + qi) * 129 + d0 + di] = acc[qi][di] * rs[di];
        __syncthreads();
        // ---- per-query running top-10 over this tile ----
        if (tid < 64 && tid < Q) {
            int rem = Ndocs - d0g;
            if (rem > TILE_D) rem = TILE_D;
            for (int j = 0; j < rem; ++j)
                topk_insert(sc, id, scb[tid * 129 + j], d0g + j);
        }
        __syncthreads();  // protect scb before next tile's staging
    }
    if (tid < 64 && tid < Q) {
        size_t base = ((size_t)blockIdx.x * Q + tid) * TOPK;
#pragma unroll
        for (int j = 0; j < TOPK; ++j) {
            cand_sc[base + j] = sc[j];
            cand_id[base + j] = id[j];
        }
    }
}

// ---------------------------------------------------------------------------
// Phase 2: per query, merge nlists sorted top-10 lists -> final top-10.
// out[q*10+j] = (float)index, out[score_off + q*10+j] = score.
// ---------------------------------------------------------------------------
__global__ void merge_kernel(const float* __restrict__ cand_sc,
                             const int* __restrict__ cand_id,
                             float* __restrict__ out,
                             int Q, int nlists, int score_off) {
    const int q = blockIdx.x;
    const int t = threadIdx.x;  // 256
    __shared__ float lsc[256 * TOPK];
    __shared__ int   lid[256 * TOPK];

    float sc[TOPK];
    int   id[TOPK];
#pragma unroll
    for (int j = 0; j < TOPK; ++j) { sc[j] = -INFINITY; id[j] = 0; }

    for (int b = t; b < nlists; b += 256) {
        size_t base = ((size_t)b * Q + q) * TOPK;
#pragma unroll
        for (int j = 0; j < TOPK; ++j) {
            float v = cand_sc[base + j];
            topk_insert(sc, id, v, cand_id[base + j]);
        }
    }
#pragma unroll
    for (int j = 0; j < TOPK; ++j) {
        lsc[t * TOPK + j] = sc[j];
        lid[t * TOPK + j] = id[j];
    }
    __syncthreads();
    for (int s = 128; s >= 1; s >>= 1) {
        if (t < s) {
            int a = t, b2 = t + s;
            int ia = 0, ib = 0;
            float msc[TOPK];
            int   mid[TOPK];
#pragma unroll
            for (int j = 0; j < TOPK; ++j) {
                float va = lsc[a * TOPK + ia];
                float vb = lsc[b2 * TOPK + ib];
                bool ta = va >= vb;
                msc[j] = ta ? va : vb;
                mid[j] = ta ? lid[a * TOPK + ia] : lid[b2 * TOPK + ib];
                ia += ta ? 1 : 0;
                ib += ta ? 0 : 1;
            }
#pragma unroll
            for (int j = 0; j < TOPK; ++j) {
                lsc[t * TOPK + j] = msc[j];
                lid[t * TOPK + j] = mid[j];
            }
        }
        __syncthreads();
    }
    if (t < TOPK) {
        out[q * TOPK + t] = (float)lid[t];
        out[score_off + q * TOPK + t] = lsc[t];
    }
}

// ---------------------------------------------------------------------------
extern "C" void kernel_launch(void* const* d_in, const int* in_sizes, int n_in,
                              void* d_out, int out_size, void* d_ws, size_t ws_size,
                              hipStream_t stream) {
    const float* q    = (const float*)d_in[0];
    const float* docs = (const float*)d_in[1];
    const int Q = in_sizes[0] / DD;   // 64
    const int N = in_sizes[1] / DD;   // 500000

    // workspace layout: qn[64*768] f32 | cand_sc[nblk*Q*10] f32 | cand_id[...] i32
    float* qn = (float*)d_ws;
    const size_t qfloats = (size_t)64 * DD;
    size_t avail = (ws_size > qfloats * 4) ? (ws_size - qfloats * 4) : 0;
    size_t per_list = (size_t)Q * TOPK * 8;
    int ntiles = (N + TILE_D - 1) / TILE_D;
    int nblk = NBLK_MAX;
    if ((size_t)nblk * per_list > avail) nblk = (int)(avail / per_list);
    if (nblk < 1) nblk = 1;
    if (nblk > ntiles) nblk = ntiles;

    float* cand_sc = qn + qfloats;
    int*   cand_id = (int*)(cand_sc + (size_t)nblk * Q * TOPK);

    hipLaunchKernelGGL(qnorm_kernel, dim3(64), dim3(256), 0, stream, q, qn, Q);
    hipLaunchKernelGGL(score_kernel, dim3(nblk), dim3(256), 0, stream,
                       qn, docs, cand_sc, cand_id, N, ntiles, Q);
    hipLaunchKernelGGL(merge_kernel, dim3(Q), dim3(256), 0, stream,
                       cand_sc, cand_id, (float*)d_out, Q, nblk, out_size / 2);
}

// Round 3
// 471.356 us; speedup vs baseline: 1.9129x; 1.9129x over previous
//
#include <hip/hip_runtime.h>
#include <math.h>

#define DD 768
#define QN 64
#define TN 128
#define BK 64
#define NSLICE (DD / BK)   // 12
#define TOPK 10
#define CAND 32
#define NBLK 512

typedef short bf16x8 __attribute__((ext_vector_type(8)));
typedef float f32x4  __attribute__((ext_vector_type(4)));

// float -> bf16 round-to-nearest-even
__device__ __forceinline__ unsigned short f2bf(float f) {
    unsigned int u = __float_as_uint(f);
    u = (u + 0x7fffu + ((u >> 16) & 1u)) >> 16;
    return (unsigned short)u;
}

// ---------------------------------------------------------------------------
// top-10 sorted insert (descending), fully unrolled -> stays in VGPRs
// ---------------------------------------------------------------------------
__device__ __forceinline__ void topk_insert(float (&sc)[TOPK], int (&id)[TOPK],
                                            float v, int nid) {
    if (v <= sc[TOPK - 1]) return;
#pragma unroll
    for (int j = TOPK - 1; j >= 1; --j) {
        bool gtj   = v > sc[j];
        bool gtjm1 = v > sc[j - 1];
        float cs = gtjm1 ? sc[j - 1] : v;
        int   ci = gtjm1 ? id[j - 1] : nid;
        sc[j] = gtj ? cs : sc[j];
        id[j] = gtj ? ci : id[j];
    }
    bool gt0 = v > sc[0];
    sc[0] = gt0 ? v : sc[0];
    id[0] = gt0 ? nid : id[0];
}

// ---------------------------------------------------------------------------
// Phase 0: L2-normalize queries (fp32 math), emit bf16 [64][768]
// ---------------------------------------------------------------------------
__global__ void qnorm_kernel(const float* __restrict__ q,
                             unsigned short* __restrict__ qn) {
    const int row = blockIdx.x;
    const int t = threadIdx.x;  // 256
    float vals[3];
    float s = 0.f;
#pragma unroll
    for (int i = 0; i < 3; ++i) {
        vals[i] = q[row * DD + i * 256 + t];
        s += vals[i] * vals[i];
    }
#pragma unroll
    for (int o = 32; o; o >>= 1) s += __shfl_down(s, o);
    __shared__ float red[4];
    if ((t & 63) == 0) red[t >> 6] = s;
    __syncthreads();
    float tot = red[0] + red[1] + red[2] + red[3];
    float inv = 1.f / fmaxf(sqrtf(tot), 1e-12f);
#pragma unroll
    for (int i = 0; i < 3; ++i)
        qn[row * DD + i * 256 + t] = f2bf(vals[i] * inv);
}

// ---------------------------------------------------------------------------
// Phase 1: MFMA bf16 approx scores, 128-doc tiles, persistent blocks,
// per-block running top-10 (filter only — exact rescore later).
// LDS tiles swizzled with byte ^= (row&7)<<4 (row stride 128B -> else 16-way).
// ---------------------------------------------------------------------------
__global__ __launch_bounds__(256, 2)
void score_kernel(const unsigned short* __restrict__ qn,
                  const float* __restrict__ docs,
                  float* __restrict__ cand_sc, int* __restrict__ cand_id,
                  int Ndocs, int ntiles) {
    __shared__ unsigned short atile[QN * BK];   // 8 KB  (queries, bf16)
    __shared__ unsigned short btile[TN * BK];   // 16 KB (docs, bf16)
    __shared__ float scb[QN * 133];             // 34 KB score buffer
    __shared__ float dnormp[TN * 8];            // 4 KB  doc sumsq partials
    __shared__ float dinv[TN];

    const int tid  = threadIdx.x;
    const int lane = tid & 63;
    const int wv   = tid >> 6;     // wave id 0..3 -> doc cols [wv*32, wv*32+32)
    const int r0   = tid >> 3;     // staging base row (0..31)
    const int c8   = tid & 7;      // 16B bf16 / 32B fp32 chunk column

    float sc[TOPK];
    int   id[TOPK];
#pragma unroll
    for (int j = 0; j < TOPK; ++j) { sc[j] = -INFINITY; id[j] = 0; }

    for (int tile = blockIdx.x; tile < ntiles; tile += gridDim.x) {
        const int d0g = tile * TN;

        f32x4 acc[4][2];
#pragma unroll
        for (int m = 0; m < 4; ++m)
#pragma unroll
            for (int n = 0; n < 2; ++n)
#pragma unroll
                for (int v = 0; v < 4; ++v) acc[m][n][v] = 0.f;
        float dnp[4] = {0.f, 0.f, 0.f, 0.f};

        float4 rb[4][2];   // doc fp32 in flight (4 rows x 8 floats)
        uint4  ra[2];      // query bf16 in flight (2 rows x 8 bf16)

        auto LOADB = [&](int kk) {
#pragma unroll
            for (int i = 0; i < 4; ++i) {
                int row = i * 32 + r0;
                int gd = d0g + row;
                if (gd < Ndocs) {
                    const float* p = docs + (size_t)gd * DD + kk + c8 * 8;
                    rb[i][0] = *(const float4*)(p);
                    rb[i][1] = *(const float4*)(p + 4);
                } else {
                    rb[i][0] = make_float4(0.f, 0.f, 0.f, 0.f);
                    rb[i][1] = make_float4(0.f, 0.f, 0.f, 0.f);
                }
            }
        };
        auto LOADA = [&](int kk) {
#pragma unroll
            for (int i = 0; i < 2; ++i) {
                int row = i * 32 + r0;
                ra[i] = *(const uint4*)(qn + row * DD + kk + c8 * 8);
            }
        };
        auto STORE = [&]() {
#pragma unroll
            for (int i = 0; i < 2; ++i) {
                int row = i * 32 + r0;
                int off = (row * 128 + c8 * 16) ^ ((row & 7) << 4);
                *(uint4*)((char*)atile + off) = ra[i];
            }
#pragma unroll
            for (int i = 0; i < 4; ++i) {
                int row = i * 32 + r0;
                float4 a = rb[i][0], b = rb[i][1];
                dnp[i] += a.x * a.x + a.y * a.y + a.z * a.z + a.w * a.w
                        + b.x * b.x + b.y * b.y + b.z * b.z + b.w * b.w;
                uint4 w;
                w.x = (unsigned)f2bf(a.x) | ((unsigned)f2bf(a.y) << 16);
                w.y = (unsigned)f2bf(a.z) | ((unsigned)f2bf(a.w) << 16);
                w.z = (unsigned)f2bf(b.x) | ((unsigned)f2bf(b.y) << 16);
                w.w = (unsigned)f2bf(b.z) | ((unsigned)f2bf(b.w) << 16);
                int off = (row * 128 + c8 * 16) ^ ((row & 7) << 4);
                *(uint4*)((char*)btile + off) = w;
            }
        };

        LOADA(0);
        LOADB(0);
        for (int s = 0; s < NSLICE; ++s) {
            __syncthreads();            // LDS tiles free for overwrite
            STORE();
            if (s + 1 < NSLICE) {       // T14: next loads in flight across MFMA
                LOADA((s + 1) * BK);
                LOADB((s + 1) * BK);
            }
            __syncthreads();            // tiles staged
            const int fr = lane & 15, fk = lane >> 4;
#pragma unroll
            for (int kc = 0; kc < 2; ++kc) {
                bf16x8 af[4];
#pragma unroll
                for (int m = 0; m < 4; ++m) {
                    int row = m * 16 + fr;
                    int off = (row * 128 + kc * 64 + fk * 16) ^ ((row & 7) << 4);
                    af[m] = *(const bf16x8*)((const char*)atile + off);
                }
                bf16x8 bfr[2];
#pragma unroll
                for (int n = 0; n < 2; ++n) {
                    int row = wv * 32 + n * 16 + fr;
                    int off = (row * 128 + kc * 64 + fk * 16) ^ ((row & 7) << 4);
                    bfr[n] = *(const bf16x8*)((const char*)btile + off);
                }
#pragma unroll
                for (int m = 0; m < 4; ++m)
#pragma unroll
                    for (int n = 0; n < 2; ++n)
                        acc[m][n] = __builtin_amdgcn_mfma_f32_16x16x32_bf16(
                            af[m], bfr[n], acc[m][n], 0, 0, 0);
            }
        }

        // ---- doc norms: reduce 8 partials per doc ----
        __syncthreads();
#pragma unroll
        for (int i = 0; i < 4; ++i)
            dnormp[(i * 32 + r0) * 8 + c8] = dnp[i];
        __syncthreads();
        if (tid < TN) {
            float s = 0.f;
#pragma unroll
            for (int j = 0; j < 8; ++j) s += dnormp[tid * 8 + j];
            dinv[tid] = 1.f / fmaxf(sqrtf(s), 1e-12f);
        }
        __syncthreads();

        // ---- scale + scatter scores to LDS ----
        {
            const int fr = lane & 15, fq4 = (lane >> 4) * 4;
#pragma unroll
            for (int m = 0; m < 4; ++m)
#pragma unroll
                for (int n = 0; n < 2; ++n) {
                    int dcol = wv * 32 + n * 16 + fr;
                    float di = dinv[dcol];
#pragma unroll
                    for (int v = 0; v < 4; ++v)
                        scb[(m * 16 + fq4 + v) * 133 + dcol] = acc[m][n][v] * di;
                }
        }
        __syncthreads();

        // ---- per-query running top-10 over this tile ----
        if (tid < QN) {
            int rem = Ndocs - d0g;
            if (rem > TN) rem = TN;
            for (int j = 0; j < rem; ++j)
                topk_insert(sc, id, scb[tid * 133 + j], d0g + j);
        }
        // next iteration's first __syncthreads protects scb/atile/btile
    }

    if (tid < QN) {
        size_t base = ((size_t)blockIdx.x * QN + tid) * TOPK;
#pragma unroll
        for (int j = 0; j < TOPK; ++j) {
            cand_sc[base + j] = sc[j];
            cand_id[base + j] = id[j];
        }
    }
}

// ---------------------------------------------------------------------------
// Phase 2: per query, merge nlists sorted 10-lists -> global approx top-32 ids.
// First level merges two global lists per thread (pointer-chase in L2, no
// runtime-indexed register arrays); tree merge in LDS.
// ---------------------------------------------------------------------------
__global__ __launch_bounds__(256)
void merge32_kernel(const float* __restrict__ cand_sc,
                    const int* __restrict__ cand_id,
                    int* __restrict__ cand32, int nlists) {
    const int q = blockIdx.x;
    const int t = threadIdx.x;  // 256
    __shared__ float lsc[256 * CAND];  // 32 KB
    __shared__ int   lid[256 * CAND];  // 32 KB

    // ---- level 0: two-pointer merge of global lists t and t+256 (desc) ----
    {
        const bool hasA = t < nlists, hasB = t + 256 < nlists;
        const size_t baseA = ((size_t)t * QN + q) * TOPK;
        const size_t baseB = ((size_t)(t + 256) * QN + q) * TOPK;
        int ia = 0, ib = 0;
        float va = hasA ? cand_sc[baseA] : -INFINITY;
        int   xa = hasA ? cand_id[baseA] : 0;
        float vb = hasB ? cand_sc[baseB] : -INFINITY;
        int   xb = hasB ? cand_id[baseB] : 0;
        for (int j = 0; j < 2 * TOPK; ++j) {
            bool ta = va >= vb;
            lsc[t * CAND + j] = ta ? va : vb;
            lid[t * CAND + j] = ta ? xa : xb;
            if (ta) {
                ++ia;
                bool ok = hasA && ia < TOPK;
                va = ok ? cand_sc[baseA + ia] : -INFINITY;
                xa = ok ? cand_id[baseA + ia] : 0;
            } else {
                ++ib;
                bool ok = hasB && ib < TOPK;
                vb = ok ? cand_sc[baseB + ib] : -INFINITY;
                xb = ok ? cand_id[baseB + ib] : 0;
            }
        }
        for (int j = 2 * TOPK; j < CAND; ++j) {
            lsc[t * CAND + j] = -INFINITY;
            lid[t * CAND + j] = 0;
        }
    }
    __syncthreads();

    // ---- tree: 128 -> 1, keep top-32 at each node ----
    for (int s = 128; s >= 1; s >>= 1) {
        if (t < s) {
            int ia = 0, ib = 0;
            float rs[CAND];
            int   ri[CAND];
#pragma unroll
            for (int j = 0; j < CAND; ++j) {
                float va = lsc[t * CAND + ia];
                float vb = lsc[(t + s) * CAND + ib];
                bool ta = va >= vb;
                rs[j] = ta ? va : vb;
                ri[j] = ta ? lid[t * CAND + ia] : lid[(t + s) * CAND + ib];
                ia += ta ? 1 : 0;
                ib += ta ? 0 : 1;
            }
#pragma unroll
            for (int j = 0; j < CAND; ++j) {
                lsc[t * CAND + j] = rs[j];
                lid[t * CAND + j] = ri[j];
            }
        }
        __syncthreads();
    }
    if (t < CAND) cand32[q * CAND + t] = lid[t];
}

// ---------------------------------------------------------------------------
// Phase 3: exact fp32 rescore of 32 candidates per query (double accumulate),
// final top-10 by rank-count with (score desc, index asc) tie-break.
// ---------------------------------------------------------------------------
__global__ __launch_bounds__(256)
void rescore_kernel(const float* __restrict__ q, const float* __restrict__ docs,
                    const int* __restrict__ cand32, float* __restrict__ out,
                    int score_off) {
    const int qi = blockIdx.x;
    const int t = threadIdx.x, lane = t & 63, wv = t >> 6;
    __shared__ float qbuf[DD];
    __shared__ float red[4];
    __shared__ float csc[CAND];
    __shared__ int   cid[CAND];

    // load + exact-normalize q row (fp32, matching reference elementwise)
    float v[3];
    float ss = 0.f;
#pragma unroll
    for (int i = 0; i < 3; ++i) {
        v[i] = q[qi * DD + i * 256 + t];
        ss += v[i] * v[i];
    }
#pragma unroll
    for (int o = 32; o; o >>= 1) ss += __shfl_down(ss, o);
    if (lane == 0) red[wv] = ss;
    __syncthreads();
    float qnorm = fmaxf(sqrtf(red[0] + red[1] + red[2] + red[3]), 1e-12f);
#pragma unroll
    for (int i = 0; i < 3; ++i) qbuf[i * 256 + t] = v[i] / qnorm;
    __syncthreads();

    for (int c = wv; c < CAND; c += 4) {
        const int d = cand32[qi * CAND + c];
        const float* dp = docs + (size_t)d * DD;
        float dss = 0.f;
#pragma unroll
        for (int j = 0; j < 3; ++j) {
            float4 dv = *(const float4*)(dp + j * 256 + lane * 4);
            dss += dv.x * dv.x + dv.y * dv.y + dv.z * dv.z + dv.w * dv.w;
        }
#pragma unroll
        for (int o = 32; o; o >>= 1) dss += __shfl_down(dss, o);
        dss = __shfl(dss, 0);
        float dnorm = fmaxf(sqrtf(dss), 1e-12f);
        double dot = 0.0;
#pragma unroll
        for (int j = 0; j < 3; ++j) {
            float4 dv = *(const float4*)(dp + j * 256 + lane * 4);
            float4 qv = *(const float4*)(qbuf + j * 256 + lane * 4);
            float d0 = dv.x / dnorm, d1 = dv.y / dnorm;
            float d2 = dv.z / dnorm, d3 = dv.w / dnorm;
            dot += (double)d0 * qv.x + (double)d1 * qv.y
                 + (double)d2 * qv.z + (double)d3 * qv.w;
        }
#pragma unroll
        for (int o = 32; o; o >>= 1) dot += __shfl_down(dot, o);
        if (lane == 0) { csc[c] = (float)dot; cid[c] = d; }
    }
    __syncthreads();

    if (t < CAND) {
        float s = csc[t];
        int myid = cid[t];
        int rank = 0;
        for (int j = 0; j < CAND; ++j) {
            float sj = csc[j];
            int ij = cid[j];
            rank += ((sj > s) || (sj == s && ij < myid)) ? 1 : 0;
        }
        if (rank < TOPK) {
            out[qi * TOPK + rank] = (float)myid;
            out[score_off + qi * TOPK + rank] = s;
        }
    }
}

// ---------------------------------------------------------------------------
extern "C" void kernel_launch(void* const* d_in, const int* in_sizes, int n_in,
                              void* d_out, int out_size, void* d_ws, size_t ws_size,
                              hipStream_t stream) {
    const float* q    = (const float*)d_in[0];
    const float* docs = (const float*)d_in[1];
    const int N = in_sizes[1] / DD;   // 500000

    // ws layout: qn bf16 [64*768] | cand32 int [64*32] | cand_sc f32 | cand_id i32
    unsigned short* qn = (unsigned short*)d_ws;
    const size_t qbytes = (size_t)QN * DD * 2;
    int* cand32 = (int*)((char*)d_ws + qbytes);
    const size_t c32bytes = (size_t)QN * CAND * 4;

    size_t used = qbytes + c32bytes;
    size_t avail = (ws_size > used) ? (ws_size - used) : 0;
    size_t per_list = (size_t)QN * TOPK * 8;
    int ntiles = (N + TN - 1) / TN;
    int nblk = NBLK;
    if ((size_t)nblk * per_list > avail) nblk = (int)(avail / per_list);
    if (nblk < 1) nblk = 1;
    if (nblk > ntiles) nblk = ntiles;

    float* cand_sc = (float*)((char*)d_ws + used);
    int*   cand_id = (int*)(cand_sc + (size_t)nblk * QN * TOPK);

    hipLaunchKernelGGL(qnorm_kernel, dim3(QN), dim3(256), 0, stream, q, qn);
    hipLaunchKernelGGL(score_kernel, dim3(nblk), dim3(256), 0, stream,
                       qn, docs, cand_sc, cand_id, N, ntiles);
    hipLaunchKernelGGL(merge32_kernel, dim3(QN), dim3(256), 0, stream,
                       cand_sc, cand_id, cand32, nblk);
    hipLaunchKernelGGL(rescore_kernel, dim3(QN), dim3(256), 0, stream,
                       q, docs, cand32, (float*)d_out, out_size / 2);
}